// Round 10
// baseline (57.691 us; speedup 1.0000x reference)
//
#include <hip/hip_runtime.h>

#define VOCAB 32000
#define EMB   1024
#define TPB   512
#define COLS  32                  // vocab cols per tile = one 128B line per W row
#define TILES (VOCAB / COLS)      // 1000
#define CH    512                 // emb rows per chunk -> 2KB contiguous stores
#define NCHUNK (EMB / CH)         // 2
#define CAP   256                 // match-list capacity (expected ~33/tile)

typedef float f32x4 __attribute__((ext_vector_type(4)));

// ---------------------------------------------------------------------------
// Identical to R9 except: PLAIN stores instead of nontemporal (A/B test).
// Single dispatch. Block = one 32-col vocab tile:
//   1) issue chunk-0 W loads (8 x 128B full lines / thread, in flight)
//   2) scan all tokens (int4-vectorized, L2-resident) -> LDS match list
//   3) commit regs -> LDS transposed + XOR-swizzled
//      dword addr = col*512 + (row ^ ((col>>2)<<2))  (writes 2-way=free,
//      reads conflict-free aligned ds_read_b128)
//   4) per chunk: prefetch next chunk's W loads, then stream each matched
//      token's 2KB contiguous store segment
// ---------------------------------------------------------------------------
__global__ __launch_bounds__(TPB) void tok_emb_fused(
    const float* __restrict__ W, const int* __restrict__ tokens,
    f32x4* __restrict__ out4, int n_tokens) {
    __shared__ float lds[COLS * CH];   // 64 KB
    __shared__ int   list[CAP];        // 1 KB
    __shared__ int   scnt;

    const int tile = blockIdx.x;
    const int v0   = tile * COLS;
    const int tid  = threadIdx.x;

    const int cg  = tid & 7;           // col group (4 floats); swizzle key
    const int rb  = tid >> 3;          // row base 0..63
    const int swz = cg << 2;           // row-XOR bits 2-4

    const float* wbase = W + (size_t)v0 + (size_t)(cg << 2);

    f32x4 r[8];
    auto issue = [&](int c0) {         // 8 x 128B full-line loads per thread
#pragma unroll
        for (int k = 0; k < 8; ++k)
            r[k] = *reinterpret_cast<const f32x4*>(
                wbase + (size_t)(c0 + rb + (k << 6)) * VOCAB);
    };
    auto commit = [&]() {              // regs -> LDS transpose scatter
#pragma unroll
        for (int k = 0; k < 8; ++k) {
            const int rs = (rb + (k << 6)) ^ swz;
#pragma unroll
            for (int j = 0; j < 4; ++j)
                lds[(((cg << 2) + j) << 9) + rs] = r[k][j];
        }
    };
    auto wphase = [&](int m, int ch) { // m tokens * 128 f32x4 (2KB each)
        const int base4 = ch * (CH / 4);
        const int nst = m << 7;
        for (int j = tid; j < nst; j += TPB) {
            const int ent = list[j >> 7];
            const int i   = j & 127;
            const int t   = ent >> 5;
            const int c   = ent & 31;
            const f32x4 v = *reinterpret_cast<const f32x4*>(
                lds + (c << 9) + ((i << 2) ^ ((c >> 2) << 2)));
            out4[(size_t)t * (EMB / 4) + base4 + i] = v;   // PLAIN store (A/B)
        }
    };
    auto scan = [&](int lo, int hi) {  // match tokens in [lo,hi) to this tile
        const int nv = (hi - lo) >> 2;
        for (int q = tid; q < nv; q += TPB) {
            const int4 tk = *reinterpret_cast<const int4*>(&tokens[lo + (q << 2)]);
            const int tv[4] = {tk.x, tk.y, tk.z, tk.w};
#pragma unroll
            for (int j = 0; j < 4; ++j) {
                const unsigned d = (unsigned)(tv[j] - v0);
                if (d < COLS) {
                    const int p = atomicAdd(&scnt, 1);
                    if (p < CAP) list[p] = ((lo + (q << 2) + j) << 5) | (int)d;
                }
            }
        }
        for (int i = lo + (nv << 2) + tid; i < hi; i += TPB) {
            const unsigned d = (unsigned)(tokens[i] - v0);
            if (d < COLS) {
                const int p = atomicAdd(&scnt, 1);
                if (p < CAP) list[p] = (i << 5) | (int)d;
            }
        }
    };

    // ---- main flow
    if (tid == 0) scnt = 0;
    issue(0);                          // W loads in flight during the scan
    __syncthreads();                   // scnt=0 visible
    scan(0, n_tokens);                 // hides under W-load latency
    commit();                          // drains loads into LDS
    __syncthreads();                   // list + tile staged
    const int m_total = scnt;          // block-uniform

    if (m_total <= CAP) {
        if (m_total == 0) return;
        issue(CH);                     // prefetch chunk 1 under chunk-0 stores
        wphase(m_total, 0);
        __syncthreads();               // LDS readers done
        commit();
        __syncthreads();
        wphase(m_total, 1);
    } else {
        // Structural backstop (never taken for uniform-random tokens):
        // segmented rescan, CAP tokens per segment -> list can't overflow.
        for (int lo = 0; lo < n_tokens; lo += CAP) {
            const int hi = (lo + CAP < n_tokens) ? lo + CAP : n_tokens;
            __syncthreads();
            if (tid == 0) scnt = 0;
            __syncthreads();
            scan(lo, hi);
            __syncthreads();
            const int m = scnt;
            if (m) {
                issue(0);
                commit();
                __syncthreads();
                issue(CH);
                wphase(m, 0);
                __syncthreads();
                commit();
                __syncthreads();
                wphase(m, 1);
            }
        }
    }
}

extern "C" void kernel_launch(void* const* d_in, const int* in_sizes, int n_in,
                              void* d_out, int out_size, void* d_ws, size_t ws_size,
                              hipStream_t stream) {
    const int*   tokens   = (const int*)d_in[0];   // [8*4096] int32
    const float* W        = (const float*)d_in[1]; // [1024][32000] f32
    f32x4*       out4     = (f32x4*)d_out;         // [32768][1024] f32
    const int    n_tokens = in_sizes[0];

    tok_emb_fused<<<TILES, TPB, 0, stream>>>(W, tokens, out4, n_tokens);
}

// Round 11
// 55.115 us; speedup vs baseline: 1.0467x; 1.0467x over previous
//
#include <hip/hip_runtime.h>

#define VOCAB 32000
#define EMB   1024
#define TPB   512
#define COLS  32                  // vocab cols per tile = one 128B line per W row
#define TILES (VOCAB / COLS)      // 1000
#define CH    512                 // emb rows per chunk -> 2KB contiguous nt-stores
#define NCHUNK (EMB / CH)         // 2
#define CAP   256                 // match-list capacity (expected ~33/tile)

typedef float f32x4 __attribute__((ext_vector_type(4)));

// ---------------------------------------------------------------------------
// FINAL (revert to R9, the best-measured variant: 56.4 us).
// Single dispatch. Block = one 32-col vocab tile:
//   1) issue chunk-0 W loads (8 x 128B full lines / thread, in flight)
//   2) scan all tokens (int4-vectorized, L2-resident) -> LDS match list
//      -- scan hides under the W-load latency
//   3) commit regs -> LDS transposed + XOR-swizzled
//      dword addr = col*512 + (row ^ ((col>>2)<<2))
//      staging writes: exactly 2 lanes/bank (free); token reads:
//      aligned conflict-free ds_read_b128 (swizzle only touches row bits 2-4)
//   4) per chunk: prefetch next chunk's W loads, then stream each matched
//      token's 2KB contiguous nt-store segment
// Measured floor: ~3.5 TB/s effective on this mixed scattered-read/
// scattered-write pattern; write/read granule, occupancy, conflicts,
// dispatch count, nt/plain all A/B'd flat (R3-R10).
// ---------------------------------------------------------------------------
__global__ __launch_bounds__(TPB) void tok_emb_fused(
    const float* __restrict__ W, const int* __restrict__ tokens,
    f32x4* __restrict__ out4, int n_tokens) {
    __shared__ float lds[COLS * CH];   // 64 KB
    __shared__ int   list[CAP];        // 1 KB
    __shared__ int   scnt;

    const int tile = blockIdx.x;
    const int v0   = tile * COLS;
    const int tid  = threadIdx.x;

    const int cg  = tid & 7;           // col group (4 floats); swizzle key
    const int rb  = tid >> 3;          // row base 0..63
    const int swz = cg << 2;           // row-XOR bits 2-4

    const float* wbase = W + (size_t)v0 + (size_t)(cg << 2);

    f32x4 r[8];
    auto issue = [&](int c0) {         // 8 x 128B full-line loads per thread
#pragma unroll
        for (int k = 0; k < 8; ++k)
            r[k] = *reinterpret_cast<const f32x4*>(
                wbase + (size_t)(c0 + rb + (k << 6)) * VOCAB);
    };
    auto commit = [&]() {              // regs -> LDS transpose scatter
#pragma unroll
        for (int k = 0; k < 8; ++k) {
            const int rs = (rb + (k << 6)) ^ swz;
#pragma unroll
            for (int j = 0; j < 4; ++j)
                lds[(((cg << 2) + j) << 9) + rs] = r[k][j];
        }
    };
    auto wphase = [&](int m, int ch) { // m tokens * 128 f32x4 (2KB each)
        const int base4 = ch * (CH / 4);
        const int nst = m << 7;
        for (int j = tid; j < nst; j += TPB) {
            const int ent = list[j >> 7];
            const int i   = j & 127;
            const int t   = ent >> 5;
            const int c   = ent & 31;
            const f32x4 v = *reinterpret_cast<const f32x4*>(
                lds + (c << 9) + ((i << 2) ^ ((c >> 2) << 2)));
            __builtin_nontemporal_store(
                v, &out4[(size_t)t * (EMB / 4) + base4 + i]);
        }
    };
    auto scan = [&](int lo, int hi) {  // match tokens in [lo,hi) to this tile
        const int nv = (hi - lo) >> 2;
        for (int q = tid; q < nv; q += TPB) {
            const int4 tk = *reinterpret_cast<const int4*>(&tokens[lo + (q << 2)]);
            const int tv[4] = {tk.x, tk.y, tk.z, tk.w};
#pragma unroll
            for (int j = 0; j < 4; ++j) {
                const unsigned d = (unsigned)(tv[j] - v0);
                if (d < COLS) {
                    const int p = atomicAdd(&scnt, 1);
                    if (p < CAP) list[p] = ((lo + (q << 2) + j) << 5) | (int)d;
                }
            }
        }
        for (int i = lo + (nv << 2) + tid; i < hi; i += TPB) {
            const unsigned d = (unsigned)(tokens[i] - v0);
            if (d < COLS) {
                const int p = atomicAdd(&scnt, 1);
                if (p < CAP) list[p] = (i << 5) | (int)d;
            }
        }
    };

    // ---- main flow
    if (tid == 0) scnt = 0;
    issue(0);                          // W loads in flight during the scan
    __syncthreads();                   // scnt=0 visible
    scan(0, n_tokens);                 // hides under W-load latency
    commit();                          // drains loads into LDS
    __syncthreads();                   // list + tile staged
    const int m_total = scnt;          // block-uniform

    if (m_total <= CAP) {
        if (m_total == 0) return;
        issue(CH);                     // prefetch chunk 1 under chunk-0 stores
        wphase(m_total, 0);
        __syncthreads();               // LDS readers done
        commit();
        __syncthreads();
        wphase(m_total, 1);
    } else {
        // Structural backstop (never taken for uniform-random tokens):
        // segmented rescan, CAP tokens per segment -> list can't overflow.
        for (int lo = 0; lo < n_tokens; lo += CAP) {
            const int hi = (lo + CAP < n_tokens) ? lo + CAP : n_tokens;
            __syncthreads();
            if (tid == 0) scnt = 0;
            __syncthreads();
            scan(lo, hi);
            __syncthreads();
            const int m = scnt;
            if (m) {
                issue(0);
                commit();
                __syncthreads();
                issue(CH);
                wphase(m, 0);
                __syncthreads();
                commit();
                __syncthreads();
                wphase(m, 1);
            }
        }
    }
}

extern "C" void kernel_launch(void* const* d_in, const int* in_sizes, int n_in,
                              void* d_out, int out_size, void* d_ws, size_t ws_size,
                              hipStream_t stream) {
    const int*   tokens   = (const int*)d_in[0];   // [8*4096] int32
    const float* W        = (const float*)d_in[1]; // [1024][32000] f32
    f32x4*       out4     = (f32x4*)d_out;         // [32768][1024] f32
    const int    n_tokens = in_sizes[0];

    tok_emb_fused<<<TILES, TPB, 0, stream>>>(W, tokens, out4, n_tokens);
}